// Round 1
// 317.861 us; speedup vs baseline: 1.0363x; 1.0363x over previous
//
#include <hip/hip_runtime.h>

// Depthwise transposed conv K=3, S=2, SAME. x:(8,128,128,128) NHWC fp32,
// w:(3,3,1,128) HWIO fp32 -> out:(8,256,256,128) fp32.
//
// Thread = (n, y, tg, c4): processes a strip of TQ=4 input columns
// t = 4*tg .. 4*tg+3 of input row y, producing 16 output float4s:
// out rows {2y, 2y+1} x cols {2t, 2t+1} for the 4 t values.
//
// Sliding register window: xpa = x[y,t-1], xpc = x[y-1,t-1] carried across
// the unrolled t-loop, so each x element is loaded once per consuming row
// (plus a 1-column halo at strip edges). All 9 weight taps hoisted to
// registers once per thread (amortized over 16 outputs vs 6 loads per 2
// outputs previously).
//
// Lane map: lane&31 = c4 (contiguous 512B channel segment), lane bit 5 =
// adjacent column group -> every load/store instruction covers two distinct
// fully-populated 512B segments (complete 64B lines, no intra-wave
// address duplication).
//
// out[2y+0, 2t+0] = w00*x[y,t] + w02*x[y,t-1] + w20*x[y-1,t] + w22*x[y-1,t-1]
// out[2y+0, 2t+1] = w01*x[y,t] + w21*x[y-1,t]
// out[2y+1, 2t+0] = w10*x[y,t] + w12*x[y,t-1]
// out[2y+1, 2t+1] = w11*x[y,t]

typedef float v4f __attribute__((ext_vector_type(4)));

__global__ __launch_bounds__(256) void upsample_tconv_kernel(
    const float* __restrict__ x, const float* __restrict__ w,
    float* __restrict__ out)
{
    // 8 * 128 * 32 * 32 = 1,048,576 threads
    int idx = blockIdx.x * blockDim.x + threadIdx.x;
    int c4 = idx & 31;            // float4 chunk of 128 channels
    int tg = (idx >> 5) & 31;    // input-column group of 4 (lane bit 5 = adjacent group)
    int y  = (idx >> 10) & 127;   // input row (wave-uniform)
    int n  = idx >> 17;           // batch

    // All 9 taps, loaded once per thread. w[j][i][c] -> (j*3+i)*32 + c4
    const v4f* wv = (const v4f*)w;
    v4f w00 = wv[0 * 32 + c4];
    v4f w01 = wv[1 * 32 + c4];
    v4f w02 = wv[2 * 32 + c4];
    v4f w10 = wv[3 * 32 + c4];
    v4f w11 = wv[4 * 32 + c4];
    v4f w12 = wv[5 * 32 + c4];
    v4f w20 = wv[6 * 32 + c4];
    v4f w21 = wv[7 * 32 + c4];
    v4f w22 = wv[8 * 32 + c4];

    const v4f zero = (v4f)(0.f);
    const v4f* xv = (const v4f*)x;   // ((n*128+y)*128+t)*32 + c4

    int t0 = tg << 2;
    int rowbase = ((n * 128 + y) * 128) * 32 + c4;   // x[y, 0]
    int upbase  = rowbase - 128 * 32;                // x[y-1, 0]
    bool has_up = (y > 0);                            // wave-uniform

    // Halo column t0-1 (zero at the left edge)
    v4f xpa = (t0 > 0) ? xv[rowbase + (t0 - 1) * 32] : zero;
    v4f xpc = (has_up && t0 > 0) ? xv[upbase + (t0 - 1) * 32] : zero;

    v4f* ov = (v4f*)out;
    int oy = y << 1;
    int ob0 = ((n * 256 + oy) * 256 + (t0 << 1)) * 32 + c4;  // out[2y,   2t0]
    int ob1 = ob0 + 256 * 32;                                // out[2y+1, 2t0]

    #pragma unroll
    for (int k = 0; k < 4; ++k) {
        v4f xa = xv[rowbase + (t0 + k) * 32];                 // x[y,   t]
        v4f xc = has_up ? xv[upbase + (t0 + k) * 32] : zero;  // x[y-1, t]

        v4f o_ee = w00 * xa + w02 * xpa + w20 * xc + w22 * xpc; // out[2y,  2t]
        v4f o_eo = w01 * xa + w21 * xc;                         // out[2y,  2t+1]
        v4f o_oe = w10 * xa + w12 * xpa;                        // out[2y+1,2t]
        v4f o_oo = w11 * xa;                                    // out[2y+1,2t+1]

        int o = ob0 + (k << 1) * 32;
        __builtin_nontemporal_store(o_ee, &ov[o]);
        __builtin_nontemporal_store(o_eo, &ov[o + 32]);
        o = ob1 + (k << 1) * 32;
        __builtin_nontemporal_store(o_oe, &ov[o]);
        __builtin_nontemporal_store(o_oo, &ov[o + 32]);

        xpa = xa;
        xpc = xc;
    }
}

extern "C" void kernel_launch(void* const* d_in, const int* in_sizes, int n_in,
                              void* d_out, int out_size, void* d_ws, size_t ws_size,
                              hipStream_t stream) {
    const float* x = (const float*)d_in[0];
    const float* w = (const float*)d_in[1];
    float* out = (float*)d_out;

    // 1,048,576 threads / 256 = 4096 blocks
    upsample_tconv_kernel<<<dim3(4096), dim3(256), 0, stream>>>(x, w, out);
}